// Round 9
// baseline (1055.848 us; speedup 1.0000x reference)
//
#include <hip/hip_runtime.h>
#include <hip/hip_bf16.h>

// ---------------------------------------------------------------------------
// FCx2DetHead, R9: ONE persistent mega-kernel. Evidence: per-dispatch sums
// were ~125 us of a 302 us wall -> ~175 us of inter-kernel launch gaps
// (15 serial graph nodes). All 13 stages fused; device-scope atomic grid
// barriers between phases (counters in d_ws, hipMemsetAsync-zeroed each
// call). 512 blocks x 256 thr = exactly 2 blocks/CU (60 KB LDS union,
// __launch_bounds__(256,2)) -> all blocks co-resident, barrier-safe.
// GEMM phases: R8's verified 3-slot global_load_lds pipeline (bf16 MFMA,
// fp32 split-K partials + fused reduce phases).
// ---------------------------------------------------------------------------

#define NROI 256
#define NB   8
#define INF  12544   // 256*49
#define DFC  1024
#define FCC  512

typedef __attribute__((ext_vector_type(8))) short short8;
typedef __attribute__((ext_vector_type(4))) float floatx4;

static __device__ __forceinline__ unsigned short f2bf(float f) {
    unsigned int u = __float_as_uint(f);
    unsigned int r = (u + 0x7fffu + ((u >> 16) & 1u)) >> 16;
    return (unsigned short)r;
}

static __device__ __forceinline__ void async_copy16(const void* g, void* l) {
    __builtin_amdgcn_global_load_lds(
        (const __attribute__((address_space(1))) unsigned int*)g,
        (__attribute__((address_space(3))) unsigned int*)l, 16, 0, 0);
}

union SMem {
    struct { float t[32][33]; } tr;                                   // 4.2 KB
    struct { float grid[49][16]; int base[49];
             unsigned short out[128 * 49]; } pool;                    // ~15.8 KB
    struct { unsigned short As[3][256 * 32]; float Bs[3][32 * 32]; } gm; // 60 KB
    struct { float h[1024]; } fc;                                     // 4 KB
};

// ---- grid-wide barrier (device-scope; one counter slot per barrier) --------
static __device__ __forceinline__ void gridbar(unsigned* ctr, int idx, unsigned nblk) {
    __syncthreads();
    if (threadIdx.x == 0) {
        __hip_atomic_fetch_add(&ctr[idx], 1u, __ATOMIC_ACQ_REL, __HIP_MEMORY_SCOPE_AGENT);
        while (__hip_atomic_load(&ctr[idx], __ATOMIC_ACQUIRE, __HIP_MEMORY_SCOPE_AGENT) < nblk)
            __builtin_amdgcn_s_sleep(1);
    }
    __syncthreads();
}

// ---- phase: transpose x (B,C,H,W) -> feat (B,H,W,C) ------------------------
static __device__ __forceinline__ void phase_transpose(
        const float* __restrict__ x, float* __restrict__ xT, SMem& sm) {
    int tid = threadIdx.x;
    int tx = tid & 31, ty = tid >> 5;
    for (int t = blockIdx.x; t < 1280; t += gridDim.x) {
        int b = t / 160, rem = t - b * 160;
        int cb = (rem / 20) * 32, lb = (rem % 20) * 32;
#pragma unroll
        for (int r = 0; r < 4; ++r) {
            int c = cb + ty + r * 8, l = lb + tx;
            if (l < 625) sm.tr.t[ty + r * 8][tx] = x[(size_t)(b * 256 + c) * 625 + l];
        }
        __syncthreads();
#pragma unroll
        for (int r = 0; r < 4; ++r) {
            int l = lb + ty + r * 8, c = cb + tx;
            if (l < 625) xT[((size_t)b * 625 + l) * 256 + c] = sm.tr.t[tx][ty + r * 8];
        }
        __syncthreads();
    }
}

// ---- phase: fused deformable RoI pool (prep + gather) ----------------------
static __device__ __forceinline__ void phase_pool(
        const float* __restrict__ feat, const float* __restrict__ rois,
        const float* __restrict__ off, int has_off,
        unsigned short* __restrict__ P, SMem& sm) {
    const float SSC = (float)(25.0 / 255.0);
    int q = blockIdx.x >> 8;       // channel half
    int n = blockIdx.x & 255;      // roi
    int tid = threadIdx.x;

    if (tid < 49) {
        int bin = tid;
        const float* r = rois + n * 5;
        int b = (int)r[0];
        float sw = rintf(r[1]) * SSC - 0.5f;
        float sh = rintf(r[2]) * SSC - 0.5f;
        float rw = fmaxf((rintf(r[3]) + 1.0f) * SSC - 0.5f - sw, 0.1f);
        float rh = fmaxf((rintf(r[4]) + 1.0f) * SSC - 0.5f - sh, 0.1f);
        float bw = rw / 7.0f, bh = rh / 7.0f;
        float bws = bw * 0.25f, bhs = bh * 0.25f;
        int ph = bin / 7, pw = bin - ph * 7;
        float tx = 0.f, ty = 0.f;
        if (has_off) {
            tx = off[n * 98 + bin] * 0.1f;
            ty = off[n * 98 + 49 + bin] * 0.1f;
        }
        float wstart = pw * bw + sw + tx * rw;
        float hstart = ph * bh + sh + ty * rh;
#pragma unroll
        for (int i = 0; i < 16; ++i) sm.pool.grid[bin][i] = 0.f;
        int gy0 = 0, gx0 = 0, cnt = 0;
#pragma unroll
        for (int s = 0; s < 16; ++s) {
            float fx = wstart + (s & 3) * bws;
            float fy = hstart + (s >> 2) * bhs;
            bool valid = (fx >= -0.5f) && (fx <= 24.5f) && (fy >= -0.5f) && (fy <= 24.5f);
            float xc = fminf(fmaxf(fx, 0.f), 24.f);
            float yc = fminf(fmaxf(fy, 0.f), 24.f);
            float x0f = floorf(xc), y0f = floorf(yc);
            float dx = xc - x0f, dy = yc - y0f;
            int x0 = (int)x0f, y0 = (int)y0f;
            int x1 = (int)ceilf(xc), y1 = (int)ceilf(yc);
            if (s == 0) { gy0 = y0; gx0 = x0; }
            float w00 = (1.f - dx) * (1.f - dy), w01 = dx * (1.f - dy);
            float w10 = (1.f - dx) * dy,         w11 = dx * dy;
            if (!valid) { w00 = w01 = w10 = w11 = 0.f; }
            cnt += valid ? 1 : 0;
            int ry0 = (y0 - gy0) * 4, ry1 = (y1 - gy0) * 4;
            sm.pool.grid[bin][ry0 + (x0 - gx0)] += w00;
            sm.pool.grid[bin][ry0 + (x1 - gx0)] += w01;
            sm.pool.grid[bin][ry1 + (x0 - gx0)] += w10;
            sm.pool.grid[bin][ry1 + (x1 - gx0)] += w11;
        }
        float inv = 1.0f / fmaxf((float)cnt, 1.0f);
#pragma unroll
        for (int i = 0; i < 16; ++i) sm.pool.grid[bin][i] *= inv;
        sm.pool.base[bin] = gy0 | (gx0 << 8) | (b << 16);
    }
    __syncthreads();

    int wv = tid >> 6, lane = tid & 63;
    int cbase = q * 128 + lane * 2;
    for (int bin = wv; bin < 49; bin += 4) {
        int base = sm.pool.base[bin];
        int gy0 = base & 255, gx0 = (base >> 8) & 255, b = base >> 16;
        const float4* wp = (const float4*)sm.pool.grid[bin];
        float4 w0 = wp[0], w1 = wp[1], w2 = wp[2], w3 = wp[3];
        float ww[16] = { w0.x, w0.y, w0.z, w0.w, w1.x, w1.y, w1.z, w1.w,
                         w2.x, w2.y, w2.z, w2.w, w3.x, w3.y, w3.z, w3.w };
        int rowOff[4], colOff[4];
#pragma unroll
        for (int r = 0; r < 4; ++r) {
            rowOff[r] = min(gy0 + r, 24) * 25;
            colOff[r] = min(gx0 + r, 24);
        }
        int b625 = b * 625;
        float ax = 0.f, ay = 0.f;
#pragma unroll
        for (int cell = 0; cell < 16; ++cell) {
            int pix = b625 + rowOff[cell >> 2] + colOff[cell & 3];
            float2 v = *(const float2*)(feat + (size_t)pix * 256 + cbase);
            ax += ww[cell] * v.x;
            ay += ww[cell] * v.y;
        }
        sm.pool.out[(lane * 2) * 49 + bin] = f2bf(ax);
        sm.pool.out[(lane * 2 + 1) * 49 + bin] = f2bf(ay);
    }
    __syncthreads();
    const uint2* so = (const uint2*)sm.pool.out;
    uint2* dp = (uint2*)(P + (size_t)n * INF + q * 128 * 49);
    for (int i = tid; i < 128 * 49 / 4; i += 256) dp[i] = so[i];
}

// ---- phase: split-K MFMA GEMM (BM=256=M, BN=32) -> fp32 partial slabs ------
static __device__ __forceinline__ void gemm_phase(
        const unsigned short* __restrict__ A, const float* __restrict__ Bw,
        float* __restrict__ Cpart, int N, int K, int nT, int zN, SMem& sm) {
    const int blk = blockIdx.x;
    if (blk >= nT * zN) return;
    const int tid = threadIdx.x;
    const int lane = tid & 63, wave = tid >> 6;
    const int quad = lane >> 4, l16 = lane & 15;
    const int nt = blk % nT, zi = blk / nT;
    const int n0 = nt * 32;
    const int kTot = K >> 5;
    const int kPerZ = kTot / zN, rem = kTot % zN;
    const int kStart = zi * kPerZ + (zi < rem ? zi : rem);
    const int kCount = kPerZ + (zi < rem ? 1 : 0);

    floatx4 acc[4][2];
#pragma unroll
    for (int i = 0; i < 4; ++i) { acc[i][0] = (floatx4)0.f; acc[i][1] = (floatx4)0.f; }

    const unsigned short* ag[4];
    int albase[4];
#pragma unroll
    for (int i = 0; i < 4; ++i) {
        int idx = tid + i * 256;
        int row = idx >> 2;
        int kg4 = (idx & 3) ^ ((row >> 1) & 3);       // A swizzle (global side)
        ag[i] = A + (size_t)row * K + kg4 * 8;
        albase[i] = (i * 256 + wave * 64) * 16;       // wave-uniform LDS base
    }
    const int brow = tid >> 3;
    const int bkg = (tid & 7) ^ ((brow >> 1) & 7);    // B swizzle
    const float* bg = Bw + (size_t)(n0 + brow) * K + bkg * 4;
    const int blbase = wave * 64 * 16;

    auto issue = [&](int slot, int kk) {   // kk = absolute k-step index
        int ke = kk * 32;
#pragma unroll
        for (int i = 0; i < 4; ++i)
            async_copy16(ag[i] + ke, (char*)&sm.gm.As[slot][0] + albase[i]);
        async_copy16(bg + ke, (char*)&sm.gm.Bs[slot][0] + blbase);
    };

    issue(0, kStart);
    issue(1, kStart + (kCount > 1 ? 1 : 0));

    int cur = 0;
    for (int ks = 0; ks < kCount; ++ks) {
        asm volatile("s_waitcnt vmcnt(5)" ::: "memory");   // cur slot landed
        asm volatile("s_barrier" ::: "memory");
        int pfs = cur + 2; if (pfs >= 3) pfs -= 3;
        int pfk = ks + 2; if (pfk > kCount - 1) pfk = kCount - 1;
        issue(pfs, kStart + pfk);
        short8 a[4], bf[2];
#pragma unroll
        for (int i = 0; i < 4; ++i) {
            int r = wave * 64 + i * 16 + l16;
            int sl = quad ^ ((r >> 1) & 3);
            a[i] = *(const short8*)(&sm.gm.As[cur][0] + r * 32 + sl * 8);
        }
#pragma unroll
        for (int j = 0; j < 2; ++j) {
            int r = j * 16 + l16;
            int sw8 = (r >> 1) & 7;
            int g0 = (quad * 2) ^ sw8, g1 = (quad * 2 + 1) ^ sw8;
            float4 v0 = *(const float4*)(&sm.gm.Bs[cur][0] + r * 32 + g0 * 4);
            float4 v1 = *(const float4*)(&sm.gm.Bs[cur][0] + r * 32 + g1 * 4);
            bf[j][0] = (short)f2bf(v0.x); bf[j][1] = (short)f2bf(v0.y);
            bf[j][2] = (short)f2bf(v0.z); bf[j][3] = (short)f2bf(v0.w);
            bf[j][4] = (short)f2bf(v1.x); bf[j][5] = (short)f2bf(v1.y);
            bf[j][6] = (short)f2bf(v1.z); bf[j][7] = (short)f2bf(v1.w);
        }
#pragma unroll
        for (int i = 0; i < 4; ++i)
#pragma unroll
            for (int j = 0; j < 2; ++j)
                acc[i][j] = __builtin_amdgcn_mfma_f32_16x16x32_bf16(a[i], bf[j], acc[i][j], 0, 0, 0);
        cur = cur + 1; if (cur >= 3) cur = 0;
    }
    float* Cp = Cpart + (size_t)zi * 256 * N;
#pragma unroll
    for (int i = 0; i < 4; ++i)
#pragma unroll
        for (int rr = 0; rr < 4; ++rr) {
            int row = wave * 64 + i * 16 + quad * 4 + rr;
            float* cr = Cp + (size_t)row * N + n0;
            cr[l16] = acc[i][0][rr];
            cr[16 + l16] = acc[i][1][rr];
        }
}

// ---- phase: reduce over Z + bias + optional relu + casts -------------------
static __device__ __forceinline__ void phase_reduce(
        const float* __restrict__ part, int zc, int mn4,
        const float* __restrict__ bias, int nmask, int relu,
        unsigned short* __restrict__ obf, float* __restrict__ of) {
    int idx = blockIdx.x * 256 + threadIdx.x;
    if (idx >= mn4) return;
    int idx4 = idx * 4;
    float4 acc = *(const float4*)(bias + (idx4 & nmask));
    const float4* p = (const float4*)part + idx;
    for (int z = 0; z < zc; ++z) {
        float4 v = p[(size_t)z * mn4];
        acc.x += v.x; acc.y += v.y; acc.z += v.z; acc.w += v.w;
    }
    if (relu) {
        acc.x = fmaxf(acc.x, 0.f); acc.y = fmaxf(acc.y, 0.f);
        acc.z = fmaxf(acc.z, 0.f); acc.w = fmaxf(acc.w, 0.f);
    }
    if (obf) {
        ushort4 h;
        h.x = f2bf(acc.x); h.y = f2bf(acc.y); h.z = f2bf(acc.z); h.w = f2bf(acc.w);
        *(ushort4*)(obf + idx4) = h;
    }
    if (of) *(float4*)(of + idx4) = acc;
}

// ---- phase: G3 small FC (off = relu(h2) @ w3^T + b3) -----------------------
static __device__ __forceinline__ void phase_fc(
        const float* __restrict__ h2, const float* __restrict__ w3,
        const float* __restrict__ b3, float* __restrict__ outp, SMem& sm) {
    if (blockIdx.x >= 256) return;
    int n = blockIdx.x, tid = threadIdx.x;
    for (int i = tid; i < 1024; i += 256)
        sm.fc.h[i] = fmaxf(h2[(size_t)n * 1024 + i], 0.f);
    __syncthreads();
    if (tid < 98) {
        float acc = b3[tid];
        const float* w = w3 + (size_t)tid * 1024;
        for (int k = 0; k < 1024; k += 4) {
            float4 wv = *(const float4*)(w + k);
            acc += sm.fc.h[k] * wv.x + sm.fc.h[k + 1] * wv.y +
                   sm.fc.h[k + 2] * wv.z + sm.fc.h[k + 3] * wv.w;
        }
        outp[n * 98 + tid] = acc;
    }
}

// ---- phase: head (out = relu(h4) @ box_w^T + box_b) ------------------------
static __device__ __forceinline__ void phase_head(
        const float* __restrict__ h4, const float* __restrict__ bw,
        const float* __restrict__ bb, float* __restrict__ out) {
    if (blockIdx.x >= 256) return;
    int n = blockIdx.x;
    int wave = threadIdx.x >> 6, lane = threadIdx.x & 63;
    const float* w = bw + wave * 512;
    const float* h = h4 + (size_t)n * 512;
    float a = 0.f;
#pragma unroll
    for (int i = 0; i < 8; ++i) {
        int k = lane + i * 64;
        a += fmaxf(h[k], 0.f) * w[k];
    }
#pragma unroll
    for (int o = 32; o > 0; o >>= 1) a += __shfl_down(a, o);
    if (lane == 0) out[n * 4 + wave] = a + bb[wave];
}

// ---------------------------------------------------------------------------
__global__ __launch_bounds__(256, 2) void mega_kernel(
        const float* x, const float* rois,
        const float* w1, const float* b1, const float* w2, const float* b2,
        const float* w3, const float* b3, const float* fw1, const float* fb1,
        const float* fw2, const float* fb2, const float* bxw, const float* bxb,
        float* out, unsigned* ctr,
        float* xT, unsigned short* P, unsigned short* h1b, float* h2,
        float* offb, unsigned short* h3b, float* h4, float* part,
        int z1, int z2, int z4, int z5) {
    __shared__ SMem sm;
    const unsigned nb = gridDim.x;

    phase_transpose(x, xT, sm);                                gridbar(ctr, 0, nb);
    phase_pool(xT, rois, nullptr, 0, P, sm);                   gridbar(ctr, 1, nb);
    gemm_phase(P, w1, part, DFC, INF, 32, z1, sm);             gridbar(ctr, 2, nb);
    phase_reduce(part, z1, NROI * DFC / 4, b1, DFC - 1, 1, h1b, nullptr); gridbar(ctr, 3, nb);
    gemm_phase(h1b, w2, part, DFC, DFC, 32, z2, sm);           gridbar(ctr, 4, nb);
    phase_reduce(part, z2, NROI * DFC / 4, b2, DFC - 1, 0, nullptr, h2);  gridbar(ctr, 5, nb);
    phase_fc(h2, w3, b3, offb, sm);                            gridbar(ctr, 6, nb);
    phase_pool(xT, rois, offb, 1, P, sm);                      gridbar(ctr, 7, nb);
    gemm_phase(P, fw1, part, FCC, INF, 16, z4, sm);            gridbar(ctr, 8, nb);
    phase_reduce(part, z4, NROI * FCC / 4, fb1, FCC - 1, 1, h3b, nullptr); gridbar(ctr, 9, nb);
    gemm_phase(h3b, fw2, part, FCC, FCC, 16, z5, sm);          gridbar(ctr, 10, nb);
    phase_reduce(part, z5, NROI * FCC / 4, fb2, FCC - 1, 0, nullptr, h4);  gridbar(ctr, 11, nb);
    phase_head(h4, bxw, bxb, out);
}

// ---------------------------------------------------------------------------
extern "C" void kernel_launch(void* const* d_in, const int* in_sizes, int n_in,
                              void* d_out, int out_size, void* d_ws, size_t ws_size,
                              hipStream_t stream) {
    const float* x      = (const float*)d_in[0];
    const float* rois   = (const float*)d_in[1];
    const float* off_w1 = (const float*)d_in[2];
    const float* off_b1 = (const float*)d_in[3];
    const float* off_w2 = (const float*)d_in[4];
    const float* off_b2 = (const float*)d_in[5];
    const float* off_w3 = (const float*)d_in[6];
    const float* off_b3 = (const float*)d_in[7];
    const float* fc1_w  = (const float*)d_in[8];
    const float* fc1_b  = (const float*)d_in[9];
    const float* fc2_w  = (const float*)d_in[10];
    const float* fc2_b  = (const float*)d_in[11];
    const float* box_w  = (const float*)d_in[12];
    const float* box_b  = (const float*)d_in[13];
    float* out = (float*)d_out;

    char* ws = (char*)d_ws;
    size_t o = 0;
    auto carve = [&](size_t bytes) { char* p = ws + o; o += (bytes + 255) & ~(size_t)255; return p; };
    unsigned*       ctr  = (unsigned*)carve(256);                       // barrier slots
    float*          xT   = (float*)carve((size_t)NB * 625 * 256 * 4);   // 5.12 MB
    unsigned short* P    = (unsigned short*)carve((size_t)NROI * INF * 2);
    unsigned short* h1b  = (unsigned short*)carve((size_t)NROI * DFC * 2);
    float*          h2   = (float*)carve((size_t)NROI * DFC * 4);
    float*          offb = (float*)carve((size_t)NROI * 98 * 4);
    unsigned short* h3b  = (unsigned short*)carve((size_t)NROI * FCC * 2);
    float*          h4   = (float*)carve((size_t)NROI * FCC * 4);
    size_t fixed = o;
    const size_t SLAB = (size_t)NROI * DFC * 4;   // 1 MB (G1/G2 slab)
    int z1, z2, z4, z5 = 16;                      // tier on ws_size (constant)
    if      (ws_size >= fixed + 16 * SLAB) { z1 = 16; z2 = 16; z4 = 32; }
    else if (ws_size >= fixed +  8 * SLAB) { z1 = 8;  z2 = 8;  z4 = 16; }
    else                                   { z1 = 4;  z2 = 4;  z4 = 8; z5 = 8; }
    float* part = (float*)carve((size_t)z1 * SLAB);

    hipMemsetAsync(ctr, 0, 256, stream);          // zero barrier counters
    mega_kernel<<<512, 256, 0, stream>>>(
        x, rois, off_w1, off_b1, off_w2, off_b2, off_w3, off_b3,
        fc1_w, fc1_b, fc2_w, fc2_b, box_w, box_b,
        out, ctr, xT, P, h1b, h2, offb, h3b, h4, part, z1, z2, z4, z5);
}